// Round 12
// baseline (898.222 us; speedup 1.0000x reference)
//
#include <hip/hip_runtime.h>

typedef _Float16 half8 __attribute__((ext_vector_type(8)));
typedef _Float16 half4v __attribute__((ext_vector_type(4)));
typedef __fp16 fp16x2 __attribute__((ext_vector_type(2)));
typedef unsigned int uint2v __attribute__((ext_vector_type(2)));
typedef int int4v __attribute__((ext_vector_type(4)));
typedef float float4v __attribute__((ext_vector_type(4)));
typedef float floatx16 __attribute__((ext_vector_type(16)));

#define MFMA16(a,b,c) __builtin_amdgcn_mfma_f32_32x32x16_f16((a),(b),(c),0,0,0)

// fp16 weight workspace layout (element offsets)
#define O_D0 0
#define N_D0 768
#define O_DC (O_D0 + N_D0)      // 768
#define N_DC 196608
#define O_PX (O_DC + N_DC)      // 197376
#define N_PX 65536
#define O_C1 (O_PX + N_PX)      // 262912
#define O_C2 (O_C1 + 16384)     // 279296
#define O_F  (O_C2 + 16384)     // 295680
#define W_TOTAL (O_F + 8192)    // 303872 elements

// GEMM weight tensors stored as [kk=k/16][c][k%16]: one wave's fragment
// (32 consecutive c rows, 32B each) is a contiguous 1KB block.
__global__ void wconv_kernel(const float* __restrict__ w_d0, const float* __restrict__ w_dc,
                             const float* __restrict__ w_px, const float* __restrict__ w_c1,
                             const float* __restrict__ w_c2, const float* __restrict__ w_f,
                             _Float16* __restrict__ ws) {
  int i = blockIdx.x * 256 + threadIdx.x;
  if (i >= W_TOTAL) return;
  float v; int dst;
  if (i < O_DC) {                       // d0: identity layout [t][c][ci]
    v = w_d0[i]; dst = O_D0 + i;
  } else if (i < O_PX) {                // dc: [blk][t][c][k] -> [blk][t][kk][c][k16]
    int s = i - O_DC;
    int k = s & 127; int r = s >> 7; int c = r & 127; int bt = r >> 7;
    int t = bt % 3, blk = bt / 3;
    dst = O_DC + blk * 49152 + ((t * 8 + (k >> 4)) * 128 + c) * 16 + (k & 15);
    v = w_dc[s];
  } else if (i < O_C1) {                // px
    int s = i - O_PX;
    int k = s & 127; int r = s >> 7; int c = r & 127; int blk = r >> 7;
    dst = O_PX + blk * 16384 + ((k >> 4) * 128 + c) * 16 + (k & 15);
    v = w_px[s];
  } else if (i < O_C2) {                // c1
    int s = i - O_C1;
    int k = s & 127; int c = s >> 7;
    dst = O_C1 + ((k >> 4) * 128 + c) * 16 + (k & 15);
    v = w_c1[s];
  } else if (i < O_F) {                 // c2
    int s = i - O_C2;
    int k = s & 127; int c = s >> 7;
    dst = O_C2 + ((k >> 4) * 128 + c) * 16 + (k & 15);
    v = w_c2[s];
  } else {                              // f: 64 rows
    int s = i - O_F;
    int k = s & 127; int c = s >> 7;
    dst = O_F + ((k >> 4) * 64 + c) * 16 + (k & 15);
    v = w_f[s];
  }
  ws[dst] = (_Float16)v;
}

__device__ __forceinline__ float silu_f(float v) {
  float e = __expf(-v);
  return v * __builtin_amdgcn_rcpf(1.0f + e);
}

// acc init = per-channel bias, from GLOBAL (L1-resident, loaded directly
// into the accumulator before the GEMM -> zero extra register pressure)
__device__ __forceinline__ floatx16 bias_g(const float* __restrict__ bp, int cbase) {
  floatx16 a;
#pragma unroll
  for (int g = 0; g < 4; ++g) {
    float4v v = *(const float4v*)(bp + cbase + 8 * g);
    a[4*g+0] = v[0]; a[4*g+1] = v[1]; a[4*g+2] = v[2]; a[4*g+3] = v[3];
  }
  return a;
}

// One accumulation pass (r4 structure: JIT weight loads, no spills).
// Weights = A/row operand (channels), acts = B/col operand (pixels).
// acc[mm] covers pixel rows row0 + mm*32.
template<int KSTRIDE>
__device__ __forceinline__ void gemm_pass(
    const _Float16* asrc, int row0,
    const _Float16* __restrict__ wq,
    int boff, int lk8, floatx16 acc[2])
{
  const int pb0 = row0 * 128;
  const int psw = (row0 & 15) << 3;   // same for row0 and row0+32
#pragma unroll
  for (int kk = 0; kk < 8; ++kk) {
    const int kx = (kk * 16 + lk8) ^ psw;
    half8 a0 = *(const half8*)&asrc[pb0 + kx];
    half8 a1 = *(const half8*)&asrc[pb0 + 4096 + kx];
    half8 w  = *(const half8*)&wq[kk * KSTRIDE + boff];
    acc[0] = MFMA16(w, a0, acc[0]);
    acc[1] = MFMA16(w, a1, acc[1]);
  }
}

// single-m-subtile pass (final layer, 16-wave split)
__device__ __forceinline__ void gemm_pass1(
    const _Float16* asrc, int row0,
    const _Float16* __restrict__ wq,
    int boff, int lk8, floatx16& acc)
{
  const int pb0 = row0 * 128;
  const int psw = (row0 & 15) << 3;
#pragma unroll
  for (int kk = 0; kk < 8; ++kk) {
    const int kx = (kk * 16 + lk8) ^ psw;
    half8 a0 = *(const half8*)&asrc[pb0 + kx];
    half8 w  = *(const half8*)&wq[kk * 1024 + boff];
    acc = MFMA16(w, a0, acc);
  }
}

// silu + packed fp16 store of 16 channels for pixel row p
__device__ __forceinline__ void store_silu(_Float16* dst, int p, int cbase,
                                           const floatx16& a, bool valid) {
  if (!valid) return;
  const int base = p * 128, s = (p & 15) << 3;
#pragma unroll
  for (int g = 0; g < 4; ++g) {
    fp16x2 h0 = __builtin_amdgcn_cvt_pkrtz(silu_f(a[4*g+0]), silu_f(a[4*g+1]));
    fp16x2 h1 = __builtin_amdgcn_cvt_pkrtz(silu_f(a[4*g+2]), silu_f(a[4*g+3]));
    uint2v u;
    u[0] = __builtin_bit_cast(unsigned int, h0);
    u[1] = __builtin_bit_cast(unsigned int, h1);
    *(uint2v*)&dst[base + ((cbase + 8*g) ^ s)] = u;
  }
}

// residual: Ab[pa] += silu(acc), masked; packed read + packed cvt write
__device__ __forceinline__ void resid_update(_Float16* Abp, int pa, int cbase,
                                             const floatx16& a, bool valid) {
  if (!valid) return;
  const int base = pa * 128, s = (pa & 15) << 3;
#pragma unroll
  for (int g = 0; g < 4; ++g) {
    int off = base + ((cbase + 8*g) ^ s);
    half4v r = *(const half4v*)&Abp[off];
    float n0 = (float)r[0] + silu_f(a[4*g+0]);
    float n1 = (float)r[1] + silu_f(a[4*g+1]);
    float n2 = (float)r[2] + silu_f(a[4*g+2]);
    float n3 = (float)r[3] + silu_f(a[4*g+3]);
    fp16x2 h0 = __builtin_amdgcn_cvt_pkrtz(n0, n1);
    fp16x2 h1 = __builtin_amdgcn_cvt_pkrtz(n2, n3);
    uint2v u;
    u[0] = __builtin_bit_cast(unsigned int, h0);
    u[1] = __builtin_bit_cast(unsigned int, h1);
    *(uint2v*)&Abp[off] = u;
  }
}

__global__ __launch_bounds__(1024, 1) void mixnet_kernel(
    const float* __restrict__ xin, const _Float16* __restrict__ ws,
    const float* __restrict__ b_d0, const float* __restrict__ b_dc,
    const float* __restrict__ b_px, const float* __restrict__ b_c1,
    const float* __restrict__ b_c2, const float* __restrict__ b_f,
    float* __restrict__ out)
{
  __shared__ _Float16 Ab[290 * 128];   // 74240 B, padded rows pa = f + 17
  __shared__ _Float16 Bb[256 * 128];   // 65536 B

  const int bid = blockIdx.x;
  const int b = bid >> 2, d = bid & 3;
  const int tid = threadIdx.x;
  const int wv = tid >> 6, l = tid & 63;
  const int mg = wv >> 2, ng = wv & 3;         // 4 m-groups x 4 n-groups (r4 mapping)
  const int lrow = l & 31;
  const int lk8 = (l >> 5) << 3;
  const int lhalf = l >> 5;

  static const int DYT[4][3] = {{0,0,0},{-1,0,1},{-1,0,1},{1,0,-1}};
  static const int DXT[4][3] = {{-1,0,1},{0,0,0},{-1,0,1},{-1,0,1}};
  const int sh0 = DYT[d][0] * 16 + DXT[d][0];
  const int sh2 = DYT[d][2] * 16 + DXT[d][2];

  const int p0 = mg * 64 + lrow;                    // pixel row, mm=0
  const int p1 = p0 + 32;                           // pixel row, mm=1
  const int boff = (ng * 32 + lrow) * 16 + lk8;     // weight fragment lane offset
  const int cbase = ng * 32 + 4 * lhalf;            // channel base for acc regs
  const bool v0 = (p0 >= 16) && (p0 < 255) && ((p0 & 15) < 15);
  const bool v1 = (p1 >= 16) && (p1 < 255) && ((p1 & 15) < 15);

  // ---- zero A buffer with b128 stores (pads must stay 0 forever) ----
  {
    int4v z = {0, 0, 0, 0};
    int4v* A4 = (int4v*)Ab;
    for (int i = tid; i < 290 * 128 * 2 / 16; i += 1024) A4[i] = z;
  }
  // ---- staging for initial conv in B region: Axt[256][16], wBs[128][16] ----
  _Float16* Axt = Bb;          // 4096 halves
  _Float16* wBs = Bb + 4096;   // 2048 halves
  {
    int* Bi = (int*)Bb;
    for (int i = tid; i < (4096 + 2048) / 2; i += 1024) Bi[i] = 0;
  }
  __syncthreads();
  for (int i = tid; i < 256 * 8; i += 1024) {
    int f = i >> 3, k = i & 7;
    if (k < 6) {
      int t = k >> 1, ci = k & 1;
      int y = (f >> 4) - 1 + DYT[d][t];
      int xx = (f & 15) + DXT[d][t];
      float v = 0.0f;
      if (y >= 0 && y < 15 && xx >= 0 && xx < 15)
        v = xin[b * 450 + ci * 225 + y * 15 + xx];
      Axt[f * 16 + k] = (_Float16)v;
    }
  }
  for (int i = tid; i < 128 * 8; i += 1024) {
    int c = i >> 3, k = i & 7;
    if (k < 6) {
      int t = k >> 1, ci = k & 1;
      wBs[c * 16 + k] = ws[O_D0 + (t * 128 + c) * 2 + ci];
    }
  }
  __syncthreads();

  // ---- initial dirconv: one K=16 MFMA per m-subtile ----
  {
    half8 a0 = *(const half8*)&Axt[p0 * 16 + lk8];
    half8 a1 = *(const half8*)&Axt[p1 * 16 + lk8];
    half8 w  = *(const half8*)&wBs[(ng * 32 + lrow) * 16 + lk8];
    floatx16 acc0 = bias_g(b_d0, cbase);
    floatx16 acc1 = acc0;
    acc0 = MFMA16(w, a0, acc0);
    acc1 = MFMA16(w, a1, acc1);
    __syncthreads();   // all reads of Axt/wBs (Bb region) complete
    store_silu(Ab, p0 + 17, cbase, acc0, v0);
    store_silu(Ab, p1 + 17, cbase, acc1, v1);
  }
  __syncthreads();

  floatx16 acc[2];
  const _Float16* wdc = ws + O_DC;
  const _Float16* wpx = ws + O_PX;

#pragma unroll 1
  for (int blk = 0; blk < 4; ++blk) {
    // dirconv: A -> silu -> B ; three accumulation passes (taps outermost)
    {
      const _Float16* wt = wdc + blk * 49152;
      acc[0] = bias_g(b_dc + blk * 128, cbase);
      acc[1] = acc[0];
      gemm_pass<2048>(Ab, 17 + p0 + sh0, wt,         boff, lk8, acc);
      gemm_pass<2048>(Ab, 17 + p0,       wt + 16384, boff, lk8, acc);
      gemm_pass<2048>(Ab, 17 + p0 + sh2, wt + 32768, boff, lk8, acc);
      store_silu(Bb, p0, cbase, acc[0], true);
      store_silu(Bb, p1, cbase, acc[1], true);
    }
    __syncthreads();
    // 1x1: B -> silu -> residual add into A (masked)
    {
      acc[0] = bias_g(b_px + blk * 128, cbase);
      acc[1] = acc[0];
      gemm_pass<2048>(Bb, p0, wpx + blk * 16384, boff, lk8, acc);
      resid_update(Ab, p0 + 17, cbase, acc[0], v0);
      resid_update(Ab, p1 + 17, cbase, acc[1], v1);
    }
    __syncthreads();
  }

  // ---- Conv0dResBlock ----
  {
    acc[0] = bias_g(b_c1, cbase);
    acc[1] = acc[0];
    gemm_pass<2048>(Ab, 17 + p0, ws + O_C1, boff, lk8, acc);
    store_silu(Bb, p0, cbase, acc[0], true);
    store_silu(Bb, p1, cbase, acc[1], true);
  }
  __syncthreads();
  {
    acc[0] = bias_g(b_c2, cbase);
    acc[1] = acc[0];
    gemm_pass<2048>(Bb, p0, ws + O_C2, boff, lk8, acc);
    resid_update(Ab, p0 + 17, cbase, acc[0], v0);
    resid_update(Ab, p1 + 17, cbase, acc[1], v1);
  }
  __syncthreads();   // Ab final; also last read of Bb (c2 gemm) complete

  // ---- final 1x1 (64 out ch): ALL 16 waves, 8 m-groups x 2 n-groups ----
  {
    const int mg2 = wv >> 1, ng2 = wv & 1;
    const int p0f = mg2 * 32 + lrow;
    const int bofff = (ng2 * 32 + lrow) * 16 + lk8;
    const int cbf = ng2 * 32 + 4 * lhalf;
    floatx16 accf = bias_g(b_f, cbf);
    gemm_pass1(Ab, 17 + p0f, ws + O_F, bofff, lk8, accf);
    float* stg = (float*)Bb;   // [64][225] fp32 = 57.6 KB
    bool vf = (p0f >= 16) && (p0f < 255) && ((p0f & 15) < 15);
    if (vf) {
      int y = (p0f >> 4) - 1, xx = p0f & 15;
      int pix = y * 15 + xx;
#pragma unroll
      for (int j = 0; j < 16; ++j) {
        int c = cbf + (j & 3) + 8 * (j >> 2);
        stg[c * 225 + pix] = accf[j];
      }
    }
  }
  __syncthreads();
  {
    const float* stg = (const float*)Bb;
    const float4v* s4 = (const float4v*)stg;
    float4v* o4 = (float4v*)(out + (size_t)bid * 14400);
    for (int i = tid; i < 3600; i += 1024)
      __builtin_nontemporal_store(s4[i], &o4[i]);
  }
}

extern "C" void kernel_launch(void* const* d_in, const int* in_sizes, int n_in,
                              void* d_out, int out_size, void* d_ws, size_t ws_size,
                              hipStream_t stream) {
  (void)in_sizes; (void)n_in; (void)out_size;
  const float* x    = (const float*)d_in[0];
  const float* w_d0 = (const float*)d_in[1];
  const float* b_d0 = (const float*)d_in[2];
  const float* w_dc = (const float*)d_in[3];
  const float* b_dc = (const float*)d_in[4];
  const float* w_px = (const float*)d_in[5];
  const float* b_px = (const float*)d_in[6];
  const float* w_c1 = (const float*)d_in[7];
  const float* b_c1 = (const float*)d_in[8];
  const float* w_c2 = (const float*)d_in[9];
  const float* b_c2 = (const float*)d_in[10];
  const float* w_f  = (const float*)d_in[11];
  const float* b_f  = (const float*)d_in[12];
  float* out = (float*)d_out;
  _Float16* ws = (_Float16*)d_ws;
  if (ws_size < (size_t)W_TOTAL * sizeof(_Float16)) return;  // fail loudly

  wconv_kernel<<<(W_TOTAL + 255) / 256, 256, 0, stream>>>(w_d0, w_dc, w_px, w_c1, w_c2, w_f, ws);
  mixnet_kernel<<<4096, 1024, 0, stream>>>(x, ws, b_d0, b_dc, b_px, b_c1, b_c2, b_f, out);
}

// Round 13
// 856.393 us; speedup vs baseline: 1.0488x; 1.0488x over previous
//
#include <hip/hip_runtime.h>

typedef _Float16 half8 __attribute__((ext_vector_type(8)));
typedef _Float16 half4v __attribute__((ext_vector_type(4)));
typedef __fp16 fp16x2 __attribute__((ext_vector_type(2)));
typedef unsigned int uint2v __attribute__((ext_vector_type(2)));
typedef int int4v __attribute__((ext_vector_type(4)));
typedef float float4v __attribute__((ext_vector_type(4)));
typedef float floatx16 __attribute__((ext_vector_type(16)));

#define MFMA16(a,b,c) __builtin_amdgcn_mfma_f32_32x32x16_f16((a),(b),(c),0,0,0)

// fp16 weight workspace layout (element offsets)
#define O_D0 0
#define N_D0 768
#define O_DC (O_D0 + N_D0)      // 768
#define N_DC 196608
#define O_PX (O_DC + N_DC)      // 197376
#define N_PX 65536
#define O_C1 (O_PX + N_PX)      // 262912
#define O_C2 (O_C1 + 16384)     // 279296
#define O_F  (O_C2 + 16384)     // 295680
#define W_TOTAL (O_F + 8192)    // 303872 elements

// GEMM weight tensors stored as [kk=k/16][c][k%16]: one wave's fragment
// (32 consecutive c rows, 32B each) is a contiguous 1KB block.
__global__ void wconv_kernel(const float* __restrict__ w_d0, const float* __restrict__ w_dc,
                             const float* __restrict__ w_px, const float* __restrict__ w_c1,
                             const float* __restrict__ w_c2, const float* __restrict__ w_f,
                             _Float16* __restrict__ ws) {
  int i = blockIdx.x * 256 + threadIdx.x;
  if (i >= W_TOTAL) return;
  float v; int dst;
  if (i < O_DC) {                       // d0: identity layout [t][c][ci]
    v = w_d0[i]; dst = O_D0 + i;
  } else if (i < O_PX) {                // dc: [blk][t][c][k] -> [blk][t][kk][c][k16]
    int s = i - O_DC;
    int k = s & 127; int r = s >> 7; int c = r & 127; int bt = r >> 7;
    int t = bt % 3, blk = bt / 3;
    dst = O_DC + blk * 49152 + ((t * 8 + (k >> 4)) * 128 + c) * 16 + (k & 15);
    v = w_dc[s];
  } else if (i < O_C1) {                // px
    int s = i - O_PX;
    int k = s & 127; int r = s >> 7; int c = r & 127; int blk = r >> 7;
    dst = O_PX + blk * 16384 + ((k >> 4) * 128 + c) * 16 + (k & 15);
    v = w_px[s];
  } else if (i < O_C2) {                // c1
    int s = i - O_C1;
    int k = s & 127; int c = s >> 7;
    dst = O_C1 + ((k >> 4) * 128 + c) * 16 + (k & 15);
    v = w_c1[s];
  } else if (i < O_F) {                 // c2
    int s = i - O_C2;
    int k = s & 127; int c = s >> 7;
    dst = O_C2 + ((k >> 4) * 128 + c) * 16 + (k & 15);
    v = w_c2[s];
  } else {                              // f: 64 rows
    int s = i - O_F;
    int k = s & 127; int c = s >> 7;
    dst = O_F + ((k >> 4) * 64 + c) * 16 + (k & 15);
    v = w_f[s];
  }
  ws[dst] = (_Float16)v;
}

__device__ __forceinline__ float silu_f(float v) {
  float e = __expf(-v);
  return v * __builtin_amdgcn_rcpf(1.0f + e);
}

// acc init = per-channel bias, from GLOBAL (L1-resident, loaded directly
// into the accumulator before the GEMM -> zero extra register pressure)
__device__ __forceinline__ floatx16 bias_g(const float* __restrict__ bp, int cbase) {
  floatx16 a;
#pragma unroll
  for (int g = 0; g < 4; ++g) {
    float4v v = *(const float4v*)(bp + cbase + 8 * g);
    a[4*g+0] = v[0]; a[4*g+1] = v[1]; a[4*g+2] = v[2]; a[4*g+3] = v[3];
  }
  return a;
}

// One accumulation pass, 2-deep software pipeline: loads of step kk+1 are
// issued before the MFMAs of step kk (scalar locals only -- no arrays, no
// scratch risk). Weights = A/row operand (channels), acts = B/col operand
// (pixels). acc[mm] covers pixel rows row0 + mm*32.
template<int KSTRIDE>
__device__ __forceinline__ void gemm_pass(
    const _Float16* asrc, int row0,
    const _Float16* __restrict__ wq,
    int boff, int lk8, floatx16 acc[2])
{
  const int pb0 = row0 * 128;
  const int psw = (row0 & 15) << 3;   // same for row0 and row0+32
  int kx = lk8 ^ psw;
  half8 a0 = *(const half8*)&asrc[pb0 + kx];
  half8 a1 = *(const half8*)&asrc[pb0 + 4096 + kx];
  half8 w  = *(const half8*)&wq[boff];
#pragma unroll
  for (int kk = 0; kk < 7; ++kk) {
    const int nkx = ((kk + 1) * 16 + lk8) ^ psw;
    half8 na0 = *(const half8*)&asrc[pb0 + nkx];
    half8 na1 = *(const half8*)&asrc[pb0 + 4096 + nkx];
    half8 nw  = *(const half8*)&wq[(kk + 1) * KSTRIDE + boff];
    acc[0] = MFMA16(w, a0, acc[0]);
    acc[1] = MFMA16(w, a1, acc[1]);
    a0 = na0; a1 = na1; w = nw;
  }
  acc[0] = MFMA16(w, a0, acc[0]);
  acc[1] = MFMA16(w, a1, acc[1]);
}

// single-m-subtile pass (final layer, 16-wave split), same pipeline
__device__ __forceinline__ void gemm_pass1(
    const _Float16* asrc, int row0,
    const _Float16* __restrict__ wq,
    int boff, int lk8, floatx16& acc)
{
  const int pb0 = row0 * 128;
  const int psw = (row0 & 15) << 3;
  int kx = lk8 ^ psw;
  half8 a0 = *(const half8*)&asrc[pb0 + kx];
  half8 w  = *(const half8*)&wq[boff];
#pragma unroll
  for (int kk = 0; kk < 7; ++kk) {
    const int nkx = ((kk + 1) * 16 + lk8) ^ psw;
    half8 na0 = *(const half8*)&asrc[pb0 + nkx];
    half8 nw  = *(const half8*)&wq[(kk + 1) * 1024 + boff];
    acc = MFMA16(w, a0, acc);
    a0 = na0; w = nw;
  }
  acc = MFMA16(w, a0, acc);
}

// silu + packed fp16 store of 16 channels for pixel row p
__device__ __forceinline__ void store_silu(_Float16* dst, int p, int cbase,
                                           const floatx16& a, bool valid) {
  if (!valid) return;
  const int base = p * 128, s = (p & 15) << 3;
#pragma unroll
  for (int g = 0; g < 4; ++g) {
    fp16x2 h0 = __builtin_amdgcn_cvt_pkrtz(silu_f(a[4*g+0]), silu_f(a[4*g+1]));
    fp16x2 h1 = __builtin_amdgcn_cvt_pkrtz(silu_f(a[4*g+2]), silu_f(a[4*g+3]));
    uint2v u;
    u[0] = __builtin_bit_cast(unsigned int, h0);
    u[1] = __builtin_bit_cast(unsigned int, h1);
    *(uint2v*)&dst[base + ((cbase + 8*g) ^ s)] = u;
  }
}

// residual: Ab[pa] += silu(acc), masked; packed read + packed cvt write
__device__ __forceinline__ void resid_update(_Float16* Abp, int pa, int cbase,
                                             const floatx16& a, bool valid) {
  if (!valid) return;
  const int base = pa * 128, s = (pa & 15) << 3;
#pragma unroll
  for (int g = 0; g < 4; ++g) {
    int off = base + ((cbase + 8*g) ^ s);
    half4v r = *(const half4v*)&Abp[off];
    float n0 = (float)r[0] + silu_f(a[4*g+0]);
    float n1 = (float)r[1] + silu_f(a[4*g+1]);
    float n2 = (float)r[2] + silu_f(a[4*g+2]);
    float n3 = (float)r[3] + silu_f(a[4*g+3]);
    fp16x2 h0 = __builtin_amdgcn_cvt_pkrtz(n0, n1);
    fp16x2 h1 = __builtin_amdgcn_cvt_pkrtz(n2, n3);
    uint2v u;
    u[0] = __builtin_bit_cast(unsigned int, h0);
    u[1] = __builtin_bit_cast(unsigned int, h1);
    *(uint2v*)&Abp[off] = u;
  }
}

__global__ __launch_bounds__(1024, 1) void mixnet_kernel(
    const float* __restrict__ xin, const _Float16* __restrict__ ws,
    const float* __restrict__ b_d0, const float* __restrict__ b_dc,
    const float* __restrict__ b_px, const float* __restrict__ b_c1,
    const float* __restrict__ b_c2, const float* __restrict__ b_f,
    float* __restrict__ out)
{
  __shared__ _Float16 Ab[290 * 128];   // 74240 B, padded rows pa = f + 17
  __shared__ _Float16 Bb[256 * 128];   // 65536 B

  const int bid = blockIdx.x;
  const int b = bid >> 2, d = bid & 3;
  const int tid = threadIdx.x;
  const int wv = tid >> 6, l = tid & 63;
  const int mg = wv >> 2, ng = wv & 3;         // 4 m-groups x 4 n-groups (r4 mapping)
  const int lrow = l & 31;
  const int lk8 = (l >> 5) << 3;
  const int lhalf = l >> 5;

  static const int DYT[4][3] = {{0,0,0},{-1,0,1},{-1,0,1},{1,0,-1}};
  static const int DXT[4][3] = {{-1,0,1},{0,0,0},{-1,0,1},{-1,0,1}};
  const int sh0 = DYT[d][0] * 16 + DXT[d][0];
  const int sh2 = DYT[d][2] * 16 + DXT[d][2];

  const int p0 = mg * 64 + lrow;                    // pixel row, mm=0
  const int p1 = p0 + 32;                           // pixel row, mm=1
  const int boff = (ng * 32 + lrow) * 16 + lk8;     // weight fragment lane offset
  const int cbase = ng * 32 + 4 * lhalf;            // channel base for acc regs
  const bool v0 = (p0 >= 16) && (p0 < 255) && ((p0 & 15) < 15);
  const bool v1 = (p1 >= 16) && (p1 < 255) && ((p1 & 15) < 15);

  // ---- zero A buffer with b128 stores (pads must stay 0 forever) ----
  {
    int4v z = {0, 0, 0, 0};
    int4v* A4 = (int4v*)Ab;
    for (int i = tid; i < 290 * 128 * 2 / 16; i += 1024) A4[i] = z;
  }
  // ---- staging for initial conv in B region: Axt[256][16], wBs[128][16] ----
  _Float16* Axt = Bb;          // 4096 halves
  _Float16* wBs = Bb + 4096;   // 2048 halves
  {
    int* Bi = (int*)Bb;
    for (int i = tid; i < (4096 + 2048) / 2; i += 1024) Bi[i] = 0;
  }
  __syncthreads();
  for (int i = tid; i < 256 * 8; i += 1024) {
    int f = i >> 3, k = i & 7;
    if (k < 6) {
      int t = k >> 1, ci = k & 1;
      int y = (f >> 4) - 1 + DYT[d][t];
      int xx = (f & 15) + DXT[d][t];
      float v = 0.0f;
      if (y >= 0 && y < 15 && xx >= 0 && xx < 15)
        v = xin[b * 450 + ci * 225 + y * 15 + xx];
      Axt[f * 16 + k] = (_Float16)v;
    }
  }
  for (int i = tid; i < 128 * 8; i += 1024) {
    int c = i >> 3, k = i & 7;
    if (k < 6) {
      int t = k >> 1, ci = k & 1;
      wBs[c * 16 + k] = ws[O_D0 + (t * 128 + c) * 2 + ci];
    }
  }
  __syncthreads();

  // ---- initial dirconv: one K=16 MFMA per m-subtile ----
  {
    half8 a0 = *(const half8*)&Axt[p0 * 16 + lk8];
    half8 a1 = *(const half8*)&Axt[p1 * 16 + lk8];
    half8 w  = *(const half8*)&wBs[(ng * 32 + lrow) * 16 + lk8];
    floatx16 acc0 = bias_g(b_d0, cbase);
    floatx16 acc1 = acc0;
    acc0 = MFMA16(w, a0, acc0);
    acc1 = MFMA16(w, a1, acc1);
    __syncthreads();   // all reads of Axt/wBs (Bb region) complete
    store_silu(Ab, p0 + 17, cbase, acc0, v0);
    store_silu(Ab, p1 + 17, cbase, acc1, v1);
  }
  __syncthreads();

  floatx16 acc[2];
  const _Float16* wdc = ws + O_DC;
  const _Float16* wpx = ws + O_PX;

#pragma unroll 1
  for (int blk = 0; blk < 4; ++blk) {
    // dirconv: A -> silu -> B ; three accumulation passes (taps outermost)
    {
      const _Float16* wt = wdc + blk * 49152;
      acc[0] = bias_g(b_dc + blk * 128, cbase);
      acc[1] = acc[0];
      gemm_pass<2048>(Ab, 17 + p0 + sh0, wt,         boff, lk8, acc);
      gemm_pass<2048>(Ab, 17 + p0,       wt + 16384, boff, lk8, acc);
      gemm_pass<2048>(Ab, 17 + p0 + sh2, wt + 32768, boff, lk8, acc);
      store_silu(Bb, p0, cbase, acc[0], true);
      store_silu(Bb, p1, cbase, acc[1], true);
    }
    __syncthreads();
    // 1x1: B -> silu -> residual add into A (masked)
    {
      acc[0] = bias_g(b_px + blk * 128, cbase);
      acc[1] = acc[0];
      gemm_pass<2048>(Bb, p0, wpx + blk * 16384, boff, lk8, acc);
      resid_update(Ab, p0 + 17, cbase, acc[0], v0);
      resid_update(Ab, p1 + 17, cbase, acc[1], v1);
    }
    __syncthreads();
  }

  // ---- Conv0dResBlock ----
  {
    acc[0] = bias_g(b_c1, cbase);
    acc[1] = acc[0];
    gemm_pass<2048>(Ab, 17 + p0, ws + O_C1, boff, lk8, acc);
    store_silu(Bb, p0, cbase, acc[0], true);
    store_silu(Bb, p1, cbase, acc[1], true);
  }
  __syncthreads();
  {
    acc[0] = bias_g(b_c2, cbase);
    acc[1] = acc[0];
    gemm_pass<2048>(Bb, p0, ws + O_C2, boff, lk8, acc);
    resid_update(Ab, p0 + 17, cbase, acc[0], v0);
    resid_update(Ab, p1 + 17, cbase, acc[1], v1);
  }
  __syncthreads();   // Ab final; also last read of Bb (c2 gemm) complete

  // ---- final 1x1 (64 out ch): ALL 16 waves, 8 m-groups x 2 n-groups ----
  {
    const int mg2 = wv >> 1, ng2 = wv & 1;
    const int p0f = mg2 * 32 + lrow;
    const int bofff = (ng2 * 32 + lrow) * 16 + lk8;
    const int cbf = ng2 * 32 + 4 * lhalf;
    floatx16 accf = bias_g(b_f, cbf);
    gemm_pass1(Ab, 17 + p0f, ws + O_F, bofff, lk8, accf);
    float* stg = (float*)Bb;   // [64][225] fp32 = 57.6 KB
    bool vf = (p0f >= 16) && (p0f < 255) && ((p0f & 15) < 15);
    if (vf) {
      int y = (p0f >> 4) - 1, xx = p0f & 15;
      int pix = y * 15 + xx;
#pragma unroll
      for (int j = 0; j < 16; ++j) {
        int c = cbf + (j & 3) + 8 * (j >> 2);
        stg[c * 225 + pix] = accf[j];
      }
    }
  }
  __syncthreads();
  {
    const float* stg = (const float*)Bb;
    const float4v* s4 = (const float4v*)stg;
    float4v* o4 = (float4v*)(out + (size_t)bid * 14400);
    for (int i = tid; i < 3600; i += 1024)
      __builtin_nontemporal_store(s4[i], &o4[i]);
  }
}

extern "C" void kernel_launch(void* const* d_in, const int* in_sizes, int n_in,
                              void* d_out, int out_size, void* d_ws, size_t ws_size,
                              hipStream_t stream) {
  (void)in_sizes; (void)n_in; (void)out_size;
  const float* x    = (const float*)d_in[0];
  const float* w_d0 = (const float*)d_in[1];
  const float* b_d0 = (const float*)d_in[2];
  const float* w_dc = (const float*)d_in[3];
  const float* b_dc = (const float*)d_in[4];
  const float* w_px = (const float*)d_in[5];
  const float* b_px = (const float*)d_in[6];
  const float* w_c1 = (const float*)d_in[7];
  const float* b_c1 = (const float*)d_in[8];
  const float* w_c2 = (const float*)d_in[9];
  const float* b_c2 = (const float*)d_in[10];
  const float* w_f  = (const float*)d_in[11];
  const float* b_f  = (const float*)d_in[12];
  float* out = (float*)d_out;
  _Float16* ws = (_Float16*)d_ws;
  if (ws_size < (size_t)W_TOTAL * sizeof(_Float16)) return;  // fail loudly

  wconv_kernel<<<(W_TOTAL + 255) / 256, 256, 0, stream>>>(w_d0, w_dc, w_px, w_c1, w_c2, w_f, ws);
  mixnet_kernel<<<4096, 1024, 0, stream>>>(x, ws, b_d0, b_dc, b_px, b_c1, b_c2, b_f, out);
}

// Round 14
// 849.639 us; speedup vs baseline: 1.0572x; 1.0080x over previous
//
#include <hip/hip_runtime.h>

typedef _Float16 half8 __attribute__((ext_vector_type(8)));
typedef _Float16 half4v __attribute__((ext_vector_type(4)));
typedef __fp16 fp16x2 __attribute__((ext_vector_type(2)));
typedef unsigned int uint2v __attribute__((ext_vector_type(2)));
typedef int int4v __attribute__((ext_vector_type(4)));
typedef float float4v __attribute__((ext_vector_type(4)));
typedef float floatx16 __attribute__((ext_vector_type(16)));

#define MFMA16(a,b,c) __builtin_amdgcn_mfma_f32_32x32x16_f16((a),(b),(c),0,0,0)

// fp16 weight workspace layout (element offsets)
#define O_D0 0
#define N_D0 768
#define O_DC (O_D0 + N_D0)      // 768
#define N_DC 196608
#define O_PX (O_DC + N_DC)      // 197376
#define N_PX 65536
#define O_C1 (O_PX + N_PX)      // 262912
#define O_C2 (O_C1 + 16384)     // 279296
#define O_F  (O_C2 + 16384)     // 295680
#define W_TOTAL (O_F + 8192)    // 303872 elements

// GEMM weight tensors stored as [kk=k/16][c][k%16]: one wave's fragment
// (32 consecutive c rows, 32B each) is a contiguous 1KB block. For the
// dirconv the 3 taps are consecutive, so fragment s (s=t*8+kk) is at
// wq + s*2048 + boff -- one linear stream of 24 fragments.
__global__ void wconv_kernel(const float* __restrict__ w_d0, const float* __restrict__ w_dc,
                             const float* __restrict__ w_px, const float* __restrict__ w_c1,
                             const float* __restrict__ w_c2, const float* __restrict__ w_f,
                             _Float16* __restrict__ ws) {
  int i = blockIdx.x * 256 + threadIdx.x;
  if (i >= W_TOTAL) return;
  float v; int dst;
  if (i < O_DC) {                       // d0: identity layout [t][c][ci]
    v = w_d0[i]; dst = O_D0 + i;
  } else if (i < O_PX) {                // dc: [blk][t][c][k] -> [blk][t][kk][c][k16]
    int s = i - O_DC;
    int k = s & 127; int r = s >> 7; int c = r & 127; int bt = r >> 7;
    int t = bt % 3, blk = bt / 3;
    dst = O_DC + blk * 49152 + ((t * 8 + (k >> 4)) * 128 + c) * 16 + (k & 15);
    v = w_dc[s];
  } else if (i < O_C1) {                // px
    int s = i - O_PX;
    int k = s & 127; int r = s >> 7; int c = r & 127; int blk = r >> 7;
    dst = O_PX + blk * 16384 + ((k >> 4) * 128 + c) * 16 + (k & 15);
    v = w_px[s];
  } else if (i < O_C2) {                // c1
    int s = i - O_C1;
    int k = s & 127; int c = s >> 7;
    dst = O_C1 + ((k >> 4) * 128 + c) * 16 + (k & 15);
    v = w_c1[s];
  } else if (i < O_F) {                 // c2
    int s = i - O_C2;
    int k = s & 127; int c = s >> 7;
    dst = O_C2 + ((k >> 4) * 128 + c) * 16 + (k & 15);
    v = w_c2[s];
  } else {                              // f: 64 rows
    int s = i - O_F;
    int k = s & 127; int c = s >> 7;
    dst = O_F + ((k >> 4) * 64 + c) * 16 + (k & 15);
    v = w_f[s];
  }
  ws[dst] = (_Float16)v;
}

__device__ __forceinline__ float silu_f(float v) {
  float e = __expf(-v);
  return v * __builtin_amdgcn_rcpf(1.0f + e);
}

// acc init = per-channel bias, from GLOBAL (L1-resident)
__device__ __forceinline__ floatx16 bias_g(const float* __restrict__ bp, int cbase) {
  floatx16 a;
#pragma unroll
  for (int g = 0; g < 4; ++g) {
    float4v v = *(const float4v*)(bp + cbase + 8 * g);
    a[4*g+0] = v[0]; a[4*g+1] = v[1]; a[4*g+2] = v[2]; a[4*g+3] = v[3];
  }
  return a;
}

// Merged 3-tap dirconv pass: one 24-step software pipeline (no drain at tap
// boundaries). Acts prefetched 1 step ahead, weights 2 ahead. All scalar
// named locals -- no arrays with runtime indices, no scratch risk.
// Fragment s = t*8 + kk; weight addr = wq + s*2048 + boff (taps contiguous).
__device__ __forceinline__ void gemm_dc(
    const _Float16* asrc, int r0, int r1, int r2,
    const _Float16* __restrict__ wq,
    int boff, int lk8, floatx16 acc[2])
{
  const int pb_0 = r0 * 128, pb_1 = r1 * 128, pb_2 = r2 * 128;
  const int ps_0 = (r0 & 15) << 3, ps_1 = (r1 & 15) << 3, ps_2 = (r2 & 15) << 3;

  half8 a0, a1, na0, na1, w0, w1, w2;
  {
    const int kx = lk8 ^ ps_0;
    a0 = *(const half8*)&asrc[pb_0 + kx];
    a1 = *(const half8*)&asrc[pb_0 + 4096 + kx];
    w0 = *(const half8*)&wq[boff];
    w1 = *(const half8*)&wq[2048 + boff];
  }
#pragma unroll
  for (int s = 0; s < 24; ++s) {
    if (s + 1 < 24) {
      const int t = (s + 1) >> 3, kk = (s + 1) & 7;
      const int pb = (t == 0) ? pb_0 : (t == 1) ? pb_1 : pb_2;
      const int ps = (t == 0) ? ps_0 : (t == 1) ? ps_1 : ps_2;
      const int kx = (kk * 16 + lk8) ^ ps;
      na0 = *(const half8*)&asrc[pb + kx];
      na1 = *(const half8*)&asrc[pb + 4096 + kx];
    }
    if (s + 2 < 24)
      w2 = *(const half8*)&wq[(s + 2) * 2048 + boff];
    acc[0] = MFMA16(w0, a0, acc[0]);
    acc[1] = MFMA16(w0, a1, acc[1]);
    a0 = na0; a1 = na1; w0 = w1; w1 = w2;
  }
}

// 1x1 pass (8 steps), acts 1 ahead / weights 2 ahead.
template<int KSTRIDE>
__device__ __forceinline__ void gemm_pass(
    const _Float16* asrc, int row0,
    const _Float16* __restrict__ wq,
    int boff, int lk8, floatx16 acc[2])
{
  const int pb0 = row0 * 128;
  const int psw = (row0 & 15) << 3;
  half8 a0, a1, na0, na1, w0, w1, w2;
  {
    const int kx = lk8 ^ psw;
    a0 = *(const half8*)&asrc[pb0 + kx];
    a1 = *(const half8*)&asrc[pb0 + 4096 + kx];
    w0 = *(const half8*)&wq[boff];
    w1 = *(const half8*)&wq[KSTRIDE + boff];
  }
#pragma unroll
  for (int kk = 0; kk < 8; ++kk) {
    if (kk + 1 < 8) {
      const int nkx = ((kk + 1) * 16 + lk8) ^ psw;
      na0 = *(const half8*)&asrc[pb0 + nkx];
      na1 = *(const half8*)&asrc[pb0 + 4096 + nkx];
    }
    if (kk + 2 < 8)
      w2 = *(const half8*)&wq[(kk + 2) * KSTRIDE + boff];
    acc[0] = MFMA16(w0, a0, acc[0]);
    acc[1] = MFMA16(w0, a1, acc[1]);
    a0 = na0; a1 = na1; w0 = w1; w1 = w2;
  }
}

// single-m-subtile pass (final layer, 16-wave split), same pipeline
__device__ __forceinline__ void gemm_pass1(
    const _Float16* asrc, int row0,
    const _Float16* __restrict__ wq,
    int boff, int lk8, floatx16& acc)
{
  const int pb0 = row0 * 128;
  const int psw = (row0 & 15) << 3;
  half8 a0, na0, w0, w1, w2;
  {
    const int kx = lk8 ^ psw;
    a0 = *(const half8*)&asrc[pb0 + kx];
    w0 = *(const half8*)&wq[boff];
    w1 = *(const half8*)&wq[1024 + boff];
  }
#pragma unroll
  for (int kk = 0; kk < 8; ++kk) {
    if (kk + 1 < 8) {
      const int nkx = ((kk + 1) * 16 + lk8) ^ psw;
      na0 = *(const half8*)&asrc[pb0 + nkx];
    }
    if (kk + 2 < 8)
      w2 = *(const half8*)&wq[(kk + 2) * 1024 + boff];
    acc = MFMA16(w0, a0, acc);
    a0 = na0; w0 = w1; w1 = w2;
  }
}

// silu + packed fp16 store of 16 channels for pixel row p
__device__ __forceinline__ void store_silu(_Float16* dst, int p, int cbase,
                                           const floatx16& a, bool valid) {
  if (!valid) return;
  const int base = p * 128, s = (p & 15) << 3;
#pragma unroll
  for (int g = 0; g < 4; ++g) {
    fp16x2 h0 = __builtin_amdgcn_cvt_pkrtz(silu_f(a[4*g+0]), silu_f(a[4*g+1]));
    fp16x2 h1 = __builtin_amdgcn_cvt_pkrtz(silu_f(a[4*g+2]), silu_f(a[4*g+3]));
    uint2v u;
    u[0] = __builtin_bit_cast(unsigned int, h0);
    u[1] = __builtin_bit_cast(unsigned int, h1);
    *(uint2v*)&dst[base + ((cbase + 8*g) ^ s)] = u;
  }
}

// residual: Ab[pa] += silu(acc), masked; packed read + packed cvt write
__device__ __forceinline__ void resid_update(_Float16* Abp, int pa, int cbase,
                                             const floatx16& a, bool valid) {
  if (!valid) return;
  const int base = pa * 128, s = (pa & 15) << 3;
#pragma unroll
  for (int g = 0; g < 4; ++g) {
    int off = base + ((cbase + 8*g) ^ s);
    half4v r = *(const half4v*)&Abp[off];
    float n0 = (float)r[0] + silu_f(a[4*g+0]);
    float n1 = (float)r[1] + silu_f(a[4*g+1]);
    float n2 = (float)r[2] + silu_f(a[4*g+2]);
    float n3 = (float)r[3] + silu_f(a[4*g+3]);
    fp16x2 h0 = __builtin_amdgcn_cvt_pkrtz(n0, n1);
    fp16x2 h1 = __builtin_amdgcn_cvt_pkrtz(n2, n3);
    uint2v u;
    u[0] = __builtin_bit_cast(unsigned int, h0);
    u[1] = __builtin_bit_cast(unsigned int, h1);
    *(uint2v*)&Abp[off] = u;
  }
}

__global__ __launch_bounds__(1024, 1) void mixnet_kernel(
    const float* __restrict__ xin, const _Float16* __restrict__ ws,
    const float* __restrict__ b_d0, const float* __restrict__ b_dc,
    const float* __restrict__ b_px, const float* __restrict__ b_c1,
    const float* __restrict__ b_c2, const float* __restrict__ b_f,
    float* __restrict__ out)
{
  __shared__ _Float16 Ab[290 * 128];   // 74240 B, padded rows pa = f + 17
  __shared__ _Float16 Bb[256 * 128];   // 65536 B

  const int bid = blockIdx.x;
  const int b = bid >> 2, d = bid & 3;
  const int tid = threadIdx.x;
  const int wv = tid >> 6, l = tid & 63;
  const int mg = wv >> 2, ng = wv & 3;         // 4 m-groups x 4 n-groups (r4 mapping)
  const int lrow = l & 31;
  const int lk8 = (l >> 5) << 3;
  const int lhalf = l >> 5;

  static const int DYT[4][3] = {{0,0,0},{-1,0,1},{-1,0,1},{1,0,-1}};
  static const int DXT[4][3] = {{-1,0,1},{0,0,0},{-1,0,1},{-1,0,1}};
  const int sh0 = DYT[d][0] * 16 + DXT[d][0];
  const int sh2 = DYT[d][2] * 16 + DXT[d][2];

  const int p0 = mg * 64 + lrow;                    // pixel row, mm=0
  const int p1 = p0 + 32;                           // pixel row, mm=1
  const int boff = (ng * 32 + lrow) * 16 + lk8;     // weight fragment lane offset
  const int cbase = ng * 32 + 4 * lhalf;            // channel base for acc regs
  const bool v0 = (p0 >= 16) && (p0 < 255) && ((p0 & 15) < 15);
  const bool v1 = (p1 >= 16) && (p1 < 255) && ((p1 & 15) < 15);

  // ---- zero A buffer with b128 stores (pads must stay 0 forever) ----
  {
    int4v z = {0, 0, 0, 0};
    int4v* A4 = (int4v*)Ab;
    for (int i = tid; i < 290 * 128 * 2 / 16; i += 1024) A4[i] = z;
  }
  // ---- staging for initial conv in B region: Axt[256][16], wBs[128][16] ----
  _Float16* Axt = Bb;          // 4096 halves
  _Float16* wBs = Bb + 4096;   // 2048 halves
  {
    int* Bi = (int*)Bb;
    for (int i = tid; i < (4096 + 2048) / 2; i += 1024) Bi[i] = 0;
  }
  __syncthreads();
  for (int i = tid; i < 256 * 8; i += 1024) {
    int f = i >> 3, k = i & 7;
    if (k < 6) {
      int t = k >> 1, ci = k & 1;
      int y = (f >> 4) - 1 + DYT[d][t];
      int xx = (f & 15) + DXT[d][t];
      float v = 0.0f;
      if (y >= 0 && y < 15 && xx >= 0 && xx < 15)
        v = xin[b * 450 + ci * 225 + y * 15 + xx];
      Axt[f * 16 + k] = (_Float16)v;
    }
  }
  for (int i = tid; i < 128 * 8; i += 1024) {
    int c = i >> 3, k = i & 7;
    if (k < 6) {
      int t = k >> 1, ci = k & 1;
      wBs[c * 16 + k] = ws[O_D0 + (t * 128 + c) * 2 + ci];
    }
  }
  __syncthreads();

  // ---- initial dirconv: one K=16 MFMA per m-subtile ----
  {
    half8 a0 = *(const half8*)&Axt[p0 * 16 + lk8];
    half8 a1 = *(const half8*)&Axt[p1 * 16 + lk8];
    half8 w  = *(const half8*)&wBs[(ng * 32 + lrow) * 16 + lk8];
    floatx16 acc0 = bias_g(b_d0, cbase);
    floatx16 acc1 = acc0;
    acc0 = MFMA16(w, a0, acc0);
    acc1 = MFMA16(w, a1, acc1);
    __syncthreads();   // all reads of Axt/wBs (Bb region) complete
    store_silu(Ab, p0 + 17, cbase, acc0, v0);
    store_silu(Ab, p1 + 17, cbase, acc1, v1);
  }
  __syncthreads();

  floatx16 acc[2];
  const _Float16* wdc = ws + O_DC;
  const _Float16* wpx = ws + O_PX;

#pragma unroll 1
  for (int blk = 0; blk < 4; ++blk) {
    // dirconv: A -> silu -> B ; merged 24-step pipelined pass
    {
      acc[0] = bias_g(b_dc + blk * 128, cbase);
      acc[1] = acc[0];
      gemm_dc(Ab, 17 + p0 + sh0, 17 + p0, 17 + p0 + sh2,
              wdc + blk * 49152, boff, lk8, acc);
      store_silu(Bb, p0, cbase, acc[0], true);
      store_silu(Bb, p1, cbase, acc[1], true);
    }
    __syncthreads();
    // 1x1: B -> silu -> residual add into A (masked)
    {
      acc[0] = bias_g(b_px + blk * 128, cbase);
      acc[1] = acc[0];
      gemm_pass<2048>(Bb, p0, wpx + blk * 16384, boff, lk8, acc);
      resid_update(Ab, p0 + 17, cbase, acc[0], v0);
      resid_update(Ab, p1 + 17, cbase, acc[1], v1);
    }
    __syncthreads();
  }

  // ---- Conv0dResBlock ----
  {
    acc[0] = bias_g(b_c1, cbase);
    acc[1] = acc[0];
    gemm_pass<2048>(Ab, 17 + p0, ws + O_C1, boff, lk8, acc);
    store_silu(Bb, p0, cbase, acc[0], true);
    store_silu(Bb, p1, cbase, acc[1], true);
  }
  __syncthreads();
  {
    acc[0] = bias_g(b_c2, cbase);
    acc[1] = acc[0];
    gemm_pass<2048>(Bb, p0, ws + O_C2, boff, lk8, acc);
    resid_update(Ab, p0 + 17, cbase, acc[0], v0);
    resid_update(Ab, p1 + 17, cbase, acc[1], v1);
  }
  __syncthreads();   // Ab final; also last read of Bb (c2 gemm) complete

  // ---- final 1x1 (64 out ch): ALL 16 waves, 8 m-groups x 2 n-groups ----
  {
    const int mg2 = wv >> 1, ng2 = wv & 1;
    const int p0f = mg2 * 32 + lrow;
    const int bofff = (ng2 * 32 + lrow) * 16 + lk8;
    const int cbf = ng2 * 32 + 4 * lhalf;
    floatx16 accf = bias_g(b_f, cbf);
    gemm_pass1(Ab, 17 + p0f, ws + O_F, bofff, lk8, accf);
    float* stg = (float*)Bb;   // [64][225] fp32 = 57.6 KB
    bool vf = (p0f >= 16) && (p0f < 255) && ((p0f & 15) < 15);
    if (vf) {
      int y = (p0f >> 4) - 1, xx = p0f & 15;
      int pix = y * 15 + xx;
#pragma unroll
      for (int j = 0; j < 16; ++j) {
        int c = cbf + (j & 3) + 8 * (j >> 2);
        stg[c * 225 + pix] = accf[j];
      }
    }
  }
  __syncthreads();
  {
    const float* stg = (const float*)Bb;
    const float4v* s4 = (const float4v*)stg;
    float4v* o4 = (float4v*)(out + (size_t)bid * 14400);
    for (int i = tid; i < 3600; i += 1024)
      __builtin_nontemporal_store(s4[i], &o4[i]);
  }
}

extern "C" void kernel_launch(void* const* d_in, const int* in_sizes, int n_in,
                              void* d_out, int out_size, void* d_ws, size_t ws_size,
                              hipStream_t stream) {
  (void)in_sizes; (void)n_in; (void)out_size;
  const float* x    = (const float*)d_in[0];
  const float* w_d0 = (const float*)d_in[1];
  const float* b_d0 = (const float*)d_in[2];
  const float* w_dc = (const float*)d_in[3];
  const float* b_dc = (const float*)d_in[4];
  const float* w_px = (const float*)d_in[5];
  const float* b_px = (const float*)d_in[6];
  const float* w_c1 = (const float*)d_in[7];
  const float* b_c1 = (const float*)d_in[8];
  const float* w_c2 = (const float*)d_in[9];
  const float* b_c2 = (const float*)d_in[10];
  const float* w_f  = (const float*)d_in[11];
  const float* b_f  = (const float*)d_in[12];
  float* out = (float*)d_out;
  _Float16* ws = (_Float16*)d_ws;
  if (ws_size < (size_t)W_TOTAL * sizeof(_Float16)) return;  // fail loudly

  wconv_kernel<<<(W_TOTAL + 255) / 256, 256, 0, stream>>>(w_d0, w_dc, w_px, w_c1, w_c2, w_f, ws);
  mixnet_kernel<<<4096, 1024, 0, stream>>>(x, ws, b_d0, b_dc, b_px, b_c1, b_c2, b_f, out);
}